// Round 1
// baseline (212.495 us; speedup 1.0000x reference)
//
#include <hip/hip_runtime.h>
#include <math.h>

#define B_ROWS   1024
#define N_SAMP   8192
#define NBINS    140
#define PERIOD   1800   // sin(2*pi*bpm*n/1800) has period 1800 in n for integer bpm
#define ROWG     16     // rows per spectrum block
#define NCHUNK   16     // r-chunks per (row-group, j)
#define SPEC_T   320    // threads per spectrum block; 140*16/320 = 7 y-blocks, fully packed
#define SPEC_YB  7

__device__ __forceinline__ float wave_reduce_sum(float v) {
    #pragma unroll
    for (int off = 32; off > 0; off >>= 1) v += __shfl_xor(v, off, 64);
    return v;
}

// ---------------- Kernel 1: fused pearson moments + periodic fold of hann*pred ---------
// One block per row. Thread t owns residues r = t, t+256, ... ; for each r sums the
// q-strided samples (coalesced across threads at fixed q) into g[row][r], and
// accumulates the 5 raw moments for pearson (affine-invariant == reference's normalized).
__global__ __launch_bounds__(256) void fold_pearson(const float* __restrict__ pred,
                                                    const float* __restrict__ targ,
                                                    float* __restrict__ g,
                                                    float* __restrict__ acc) {
    const int row = blockIdx.x;
    const float* p = pred + (size_t)row * N_SAMP;
    const float* t = targ + (size_t)row * N_SAMP;
    float sx = 0.f, sy = 0.f, sxy = 0.f, sxx = 0.f, syy = 0.f;
    const float hc = 6.28318530717958647692f / 8191.0f;  // np.hanning(8192): 2*pi/(M-1)
    for (int r = threadIdx.x; r < PERIOD; r += 256) {
        float gacc = 0.f;
        #pragma unroll
        for (int q = 0; q < 5; ++q) {
            int n = r + PERIOD * q;
            if (n < N_SAMP) {
                float pv = p[n], tv = t[n];
                sx += pv; sy += tv;
                sxy = fmaf(pv, tv, sxy);
                sxx = fmaf(pv, pv, sxx);
                syy = fmaf(tv, tv, syy);
                float hann = 0.5f - 0.5f * __cosf(hc * (float)n);
                gacc = fmaf(pv, hann, gacc);
            }
        }
        g[row * PERIOD + r] = gacc;
    }
    float vals[5] = {sx, sy, sxy, sxx, syy};
    #pragma unroll
    for (int i = 0; i < 5; ++i) vals[i] = wave_reduce_sum(vals[i]);
    __shared__ float red[4][5];
    int wid = threadIdx.x >> 6, lane = threadIdx.x & 63;
    if (lane == 0) {
        #pragma unroll
        for (int i = 0; i < 5; ++i) red[wid][i] = vals[i];
    }
    __syncthreads();
    if (threadIdx.x == 0) {
        float m[5];
        #pragma unroll
        for (int i = 0; i < 5; ++i) m[i] = red[0][i] + red[1][i] + red[2][i] + red[3][i];
        const float N = (float)N_SAMP;
        float num = N * m[2] - m[0] * m[1];
        float den = sqrtf((N * m[3] - m[0] * m[0]) * (N * m[4] - m[1] * m[1]));
        atomicAdd(&acc[0], 1.0f - num / den);  // (1 - pearson) summed over rows
    }
}

// ---------------- Kernel 2: single-bin DFT on folded data (K=1800 instead of 8192) -----
// grid = (64 row-groups of 16 rows, 7); block = 320 threads.
// Global item id it in [0,2240): j = it%140 (bpm bin), chunk = it/140 (r-range).
// Each thread computes partial s,c for 16 rows over its r-chunk; phase is integer-exact
// via rm = (bpm*r) mod 1800. float4 loads of g give 4 r's per load per row.
__global__ __launch_bounds__(SPEC_T) void spectrum(const float* __restrict__ g,
                                                   float* __restrict__ sc) {
    const int it  = blockIdx.y * SPEC_T + threadIdx.x;   // [0, 2240)
    const int j   = it % NBINS;
    const int cki = it / NBINS;                          // [0, 16)
    const int bpm = 40 + j;
    const int row0 = blockIdx.x * ROWG;
    const int r0 = cki * 112;
    const int r1 = (cki == NCHUNK - 1) ? PERIOD : (r0 + 112);  // last chunk = 120
    float sa[ROWG], ca[ROWG];
    #pragma unroll
    for (int i = 0; i < ROWG; ++i) { sa[i] = 0.f; ca[i] = 0.f; }
    int rm = (bpm * r0) % PERIOD;
    const float w = 6.28318530717958647692f / (float)PERIOD;
    for (int r = r0; r < r1; r += 4) {
        float sv[4], cv[4];
        int rmt = rm;
        #pragma unroll
        for (int u = 0; u < 4; ++u) {
            __sincosf(w * (float)rmt, &sv[u], &cv[u]);
            rmt += bpm; if (rmt >= PERIOD) rmt -= PERIOD;
        }
        rm = rmt;
        #pragma unroll
        for (int i = 0; i < ROWG; ++i) {
            const float4 v = *(const float4*)(g + (row0 + i) * PERIOD + r);  // 7200B rows: 16B aligned
            sa[i] = fmaf(v.x, sv[0], sa[i]); ca[i] = fmaf(v.x, cv[0], ca[i]);
            sa[i] = fmaf(v.y, sv[1], sa[i]); ca[i] = fmaf(v.y, cv[1], ca[i]);
            sa[i] = fmaf(v.z, sv[2], sa[i]); ca[i] = fmaf(v.z, cv[2], ca[i]);
            sa[i] = fmaf(v.w, sv[3], sa[i]); ca[i] = fmaf(v.w, cv[3], ca[i]);
        }
    }
    #pragma unroll
    for (int i = 0; i < ROWG; ++i) {
        atomicAdd(&sc[(row0 + i) * 280 + j],         sa[i]);   // sin part
        atomicAdd(&sc[(row0 + i) * 280 + 140 + j],   ca[i]);   // cos part
    }
}

// ---------------- Kernel 3: per-row spectrum -> normalize -> log_softmax -> CE + KL ----
__global__ __launch_bounds__(64) void post(const float* __restrict__ sc,
                                           const int* __restrict__ hr,
                                           float* __restrict__ acc) {
    const int b = blockIdx.x;
    const int l = threadIdx.x;
    const int h = hr[b];
    float cav[3]; float casum = 0.f;
    #pragma unroll
    for (int u = 0; u < 3; ++u) {
        int k = l + 64 * u;
        float v = 0.f;
        if (k < NBINS) {
            float s = sc[b * 280 + k], c = sc[b * 280 + 140 + k];
            v = s * s + c * c;
        }
        cav[u] = v; casum += v;
    }
    casum = wave_reduce_sum(casum);
    const float inv = 1.0f / casum;
    float x[3]; float m = -1e30f;
    #pragma unroll
    for (int u = 0; u < 3; ++u) {
        int k = l + 64 * u;
        x[u] = cav[u] * inv;
        if (k < NBINS) m = fmaxf(m, x[u]);
    }
    #pragma unroll
    for (int off = 32; off > 0; off >>= 1) m = fmaxf(m, __shfl_xor(m, off, 64));
    float esum = 0.f;
    #pragma unroll
    for (int u = 0; u < 3; ++u) {
        int k = l + 64 * u;
        if (k < NBINS) esum += __expf(x[u] - m);
    }
    esum = wave_reduce_sum(esum);
    const float lse = m + __logf(esum);
    float ce = 0.f, kl = 0.f;
    #pragma unroll
    for (int u = 0; u < 3; ++u) {
        int k = l + 64 * u;
        if (k < NBINS) {
            float logp = x[u] - lse;
            if (k == h) ce = -logp;
            float d = (float)k - (float)h;
            float tt = __expf(-0.5f * d * d) * 0.39894228040143267794f; // 1/sqrt(2*pi)
            tt = fmaxf(tt, 1e-15f);
            kl += __expf(tt) * (tt - logp);
        }
    }
    ce = wave_reduce_sum(ce);
    kl = wave_reduce_sum(kl) * (1.0f / NBINS);
    if (l == 0) { atomicAdd(&acc[1], ce); atomicAdd(&acc[2], kl); }
}

// ---------------- Kernel 4: combine with curriculum alpha/beta -------------------------
__global__ void finalize(const float* __restrict__ acc, const int* __restrict__ epoch_p,
                         float* __restrict__ out) {
    if (threadIdx.x == 0 && blockIdx.x == 0) {
        float temporal = acc[0] * (1.0f / B_ROWS);
        float ce       = acc[1] * (1.0f / B_ROWS);
        float kl       = acc[2] * (1.0f / B_ROWS);
        int epoch = epoch_p[0];
        float alpha, beta;
        if (epoch > 25) { alpha = 0.05f; beta = 2.0f; }
        else {
            float e = (float)epoch / 25.0f;
            alpha = 0.1f * exp2f(-e);   // 0.5^(e/25)
            beta  = exp2f(e);           // 2^(e/25)
        }
        out[0] = alpha * temporal + beta * (ce + kl);
    }
}

extern "C" void kernel_launch(void* const* d_in, const int* in_sizes, int n_in,
                              void* d_out, int out_size, void* d_ws, size_t ws_size,
                              hipStream_t stream) {
    const int*   epoch = (const int*)d_in[0];
    const float* pred  = (const float*)d_in[1];
    const float* targ  = (const float*)d_in[2];
    const int*   hr    = (const int*)d_in[3];
    float* out = (float*)d_out;

    char* ws = (char*)d_ws;
    float* acc = (float*)ws;                                  // 3 floats (pear, ce, kl)
    float* g   = (float*)(ws + 1024);                         // 1024 x 1800 fp32 (7.37 MB)
    float* sc  = (float*)(ws + 1024 + (size_t)B_ROWS * PERIOD * 4); // 1024 x 280 fp32

    hipMemsetAsync(acc, 0, 16, stream);
    hipMemsetAsync(sc, 0, (size_t)B_ROWS * 280 * 4, stream);

    fold_pearson<<<B_ROWS, 256, 0, stream>>>(pred, targ, g, acc);
    spectrum<<<dim3(B_ROWS / ROWG, SPEC_YB), SPEC_T, 0, stream>>>(g, sc);
    post<<<B_ROWS, 64, 0, stream>>>(sc, hr, acc);
    finalize<<<1, 64, 0, stream>>>(acc, epoch, out);
}

// Round 2
// 183.478 us; speedup vs baseline: 1.1582x; 1.1582x over previous
//
#include <hip/hip_runtime.h>
#include <math.h>

#define B_ROWS   1024
#define N_SAMP   8192
#define NBINS    140
#define PERIOD   1800   // sin(2*pi*bpm*n/1800) has period 1800 in n for integer bpm
#define NQUAD    450    // PERIOD/4
#define NCOL     280    // sin|cos concatenated
#define NSPLIT   12     // K-split factor; chunk = 150
#define KCHUNK   150
#define KSTEP    25     // LDS B-tile depth; 28 KB
#define ROWS_W   8      // rows per wave
#define BLK_ROWS 32     // rows per block (4 waves)

__device__ __forceinline__ float wave_reduce_sum(float v) {
    #pragma unroll
    for (int off = 32; off > 0; off >>= 1) v += __shfl_xor(v, off, 64);
    return v;
}

// ---------------- Kernel 0: trig matrix T[k][j] (j<140: sin, j>=140: cos), integer-exact phase
__global__ __launch_bounds__(256) void trig(float* __restrict__ T) {
    int idx = blockIdx.x * 256 + threadIdx.x;
    if (idx >= PERIOD * NCOL) return;
    int k = idx / NCOL, j = idx - k * NCOL;
    int jj = (j < NBINS) ? j : j - NBINS;
    int m = ((40 + jj) * k) % PERIOD;
    float ang = (6.28318530717958647692f / (float)PERIOD) * (float)m;
    T[idx] = (j < NBINS) ? __sinf(ang) : __cosf(ang);
}

// ---------------- Kernel 1: pearson moments + periodic fold of hann*pred (float4) -------
// Residue-quads: quad qd covers residues 4qd..4qd+3; periods q=0..4; q=4 valid iff qd<248
// (8192-7200=992=4*248, exact). All loads/stores are 16B-aligned float4.
__global__ __launch_bounds__(256) void fold_pearson(const float* __restrict__ pred,
                                                    const float* __restrict__ targ,
                                                    float* __restrict__ g,
                                                    float* __restrict__ acc) {
    const int row = blockIdx.x;
    const float* p = pred + (size_t)row * N_SAMP;
    const float* t = targ + (size_t)row * N_SAMP;
    float sx[4] = {0,0,0,0}, sy[4] = {0,0,0,0}, sxy[4] = {0,0,0,0};
    float sxx[4] = {0,0,0,0}, syy[4] = {0,0,0,0};
    const float hc = 6.28318530717958647692f / 8191.0f;  // np.hanning(8192)
    for (int qd = threadIdx.x; qd < NQUAD; qd += 256) {
        float ga[4] = {0,0,0,0};
        #pragma unroll
        for (int q = 0; q < 5; ++q) {
            if (q < 4 || qd < 248) {
                const int n = 4 * qd + PERIOD * q;
                const float4 pv = *(const float4*)(p + n);
                const float4 tv = *(const float4*)(t + n);
                const float pc[4] = {pv.x, pv.y, pv.z, pv.w};
                const float tc[4] = {tv.x, tv.y, tv.z, tv.w};
                #pragma unroll
                for (int i = 0; i < 4; ++i) {
                    sx[i] += pc[i]; sy[i] += tc[i];
                    sxy[i] = fmaf(pc[i], tc[i], sxy[i]);
                    sxx[i] = fmaf(pc[i], pc[i], sxx[i]);
                    syy[i] = fmaf(tc[i], tc[i], syy[i]);
                    float h = 0.5f - 0.5f * __cosf(hc * (float)(n + i));
                    ga[i] = fmaf(pc[i], h, ga[i]);
                }
            }
        }
        *(float4*)(g + (size_t)row * PERIOD + 4 * qd) = make_float4(ga[0], ga[1], ga[2], ga[3]);
    }
    float vals[5];
    vals[0] = sx[0]+sx[1]+sx[2]+sx[3];
    vals[1] = sy[0]+sy[1]+sy[2]+sy[3];
    vals[2] = sxy[0]+sxy[1]+sxy[2]+sxy[3];
    vals[3] = sxx[0]+sxx[1]+sxx[2]+sxx[3];
    vals[4] = syy[0]+syy[1]+syy[2]+syy[3];
    #pragma unroll
    for (int i = 0; i < 5; ++i) vals[i] = wave_reduce_sum(vals[i]);
    __shared__ float red[4][5];
    int wid = threadIdx.x >> 6, lane = threadIdx.x & 63;
    if (lane == 0) {
        #pragma unroll
        for (int i = 0; i < 5; ++i) red[wid][i] = vals[i];
    }
    __syncthreads();
    if (threadIdx.x == 0) {
        float m[5];
        #pragma unroll
        for (int i = 0; i < 5; ++i) m[i] = red[0][i] + red[1][i] + red[2][i] + red[3][i];
        const float N = (float)N_SAMP;
        float num = N * m[2] - m[0] * m[1];
        float den = sqrtf((N * m[3] - m[0] * m[0]) * (N * m[4] - m[1] * m[1]));
        atomicAdd(&acc[0], 1.0f - num / den);
    }
}

// ---------------- Kernel 2: register-blocked VALU GEMM  scp[split] += g · T ------------
// grid (32 row-blocks, NSPLIT k-splits), 256 threads. Wave owns 8 rows; lane owns cols
// lane+64c (c=0..4, c=4 only lane<24). B staged in LDS; A via wave-uniform scalar loads.
// No atomics: each split writes its own partial buffer.
__global__ __launch_bounds__(256) void spectrum(const float* __restrict__ g,
                                                const float* __restrict__ T,
                                                float* __restrict__ scp) {
    __shared__ float Bt[KSTEP * NCOL];   // 28000 B
    const int lane = threadIdx.x & 63;
    const int wid  = __builtin_amdgcn_readfirstlane(threadIdx.x >> 6);
    const int row0 = blockIdx.x * BLK_ROWS + wid * ROWS_W;
    const int k0   = blockIdx.y * KCHUNK;
    float acc[ROWS_W][5];
    #pragma unroll
    for (int r = 0; r < ROWS_W; ++r)
        #pragma unroll
        for (int c = 0; c < 5; ++c) acc[r][c] = 0.f;

    for (int step = 0; step < KCHUNK / KSTEP; ++step) {
        const int kb = k0 + step * KSTEP;
        __syncthreads();
        #pragma unroll
        for (int i = 0; i < 7; ++i) {            // 7*256 >= 1750 float4s
            int idx = threadIdx.x + 256 * i;
            if (idx < (KSTEP * NCOL / 4))
                ((float4*)Bt)[idx] = ((const float4*)(T + (size_t)kb * NCOL))[idx];
        }
        __syncthreads();
        #pragma unroll 5
        for (int kk = 0; kk < KSTEP; ++kk) {
            float b[5];
            #pragma unroll
            for (int c = 0; c < 4; ++c) b[c] = Bt[kk * NCOL + lane + 64 * c];
            b[4] = (lane < 24) ? Bt[kk * NCOL + 256 + lane] : 0.f;
            const float* ga = g + (size_t)row0 * PERIOD + (kb + kk);
            #pragma unroll
            for (int r = 0; r < ROWS_W; ++r) {
                float a = ga[(size_t)r * PERIOD];   // wave-uniform -> s_load
                #pragma unroll
                for (int c = 0; c < 5; ++c) acc[r][c] = fmaf(a, b[c], acc[r][c]);
            }
        }
    }
    float* base = scp + ((size_t)blockIdx.y * B_ROWS + row0) * NCOL;
    #pragma unroll
    for (int r = 0; r < ROWS_W; ++r)
        #pragma unroll
        for (int c = 0; c < 5; ++c) {
            int col = lane + 64 * c;
            if (col < NCOL) base[(size_t)r * NCOL + col] = acc[r][c];
        }
}

// ---------------- Kernel 3: reduce splits -> power -> normalize -> log_softmax -> CE+KL -
__global__ __launch_bounds__(64) void post(const float* __restrict__ scp,
                                           const int* __restrict__ hr,
                                           float* __restrict__ acc) {
    const int b = blockIdx.x;
    const int l = threadIdx.x;
    const int h = hr[b];
    float cav[3]; float casum = 0.f;
    #pragma unroll
    for (int u = 0; u < 3; ++u) {
        int j = l + 64 * u;
        float v = 0.f;
        if (j < NBINS) {
            float s = 0.f, c = 0.f;
            #pragma unroll 4
            for (int sp = 0; sp < NSPLIT; ++sp) {
                const float* pp = scp + ((size_t)sp * B_ROWS + b) * NCOL;
                s += pp[j]; c += pp[NBINS + j];
            }
            v = fmaf(s, s, c * c);
        }
        cav[u] = v; casum += v;
    }
    casum = wave_reduce_sum(casum);
    const float inv = 1.0f / casum;
    float x[3]; float m = -1e30f;
    #pragma unroll
    for (int u = 0; u < 3; ++u) {
        int j = l + 64 * u;
        x[u] = cav[u] * inv;
        if (j < NBINS) m = fmaxf(m, x[u]);
    }
    #pragma unroll
    for (int off = 32; off > 0; off >>= 1) m = fmaxf(m, __shfl_xor(m, off, 64));
    float esum = 0.f;
    #pragma unroll
    for (int u = 0; u < 3; ++u) {
        int j = l + 64 * u;
        if (j < NBINS) esum += __expf(x[u] - m);
    }
    esum = wave_reduce_sum(esum);
    const float lse = m + __logf(esum);
    float ce = 0.f, kl = 0.f;
    #pragma unroll
    for (int u = 0; u < 3; ++u) {
        int j = l + 64 * u;
        if (j < NBINS) {
            float logp = x[u] - lse;
            if (j == h) ce = -logp;
            float d = (float)j - (float)h;
            float tt = __expf(-0.5f * d * d) * 0.39894228040143267794f;
            tt = fmaxf(tt, 1e-15f);
            kl += __expf(tt) * (tt - logp);
        }
    }
    ce = wave_reduce_sum(ce);
    kl = wave_reduce_sum(kl) * (1.0f / NBINS);
    if (l == 0) { atomicAdd(&acc[1], ce); atomicAdd(&acc[2], kl); }
}

// ---------------- Kernel 4: combine with curriculum alpha/beta -------------------------
__global__ void finalize(const float* __restrict__ acc, const int* __restrict__ epoch_p,
                         float* __restrict__ out) {
    if (threadIdx.x == 0 && blockIdx.x == 0) {
        float temporal = acc[0] * (1.0f / B_ROWS);
        float ce       = acc[1] * (1.0f / B_ROWS);
        float kl       = acc[2] * (1.0f / B_ROWS);
        int epoch = epoch_p[0];
        float alpha, beta;
        if (epoch > 25) { alpha = 0.05f; beta = 2.0f; }
        else {
            float e = (float)epoch / 25.0f;
            alpha = 0.1f * exp2f(-e);
            beta  = exp2f(e);
        }
        out[0] = alpha * temporal + beta * (ce + kl);
    }
}

extern "C" void kernel_launch(void* const* d_in, const int* in_sizes, int n_in,
                              void* d_out, int out_size, void* d_ws, size_t ws_size,
                              hipStream_t stream) {
    const int*   epoch = (const int*)d_in[0];
    const float* pred  = (const float*)d_in[1];
    const float* targ  = (const float*)d_in[2];
    const int*   hr    = (const int*)d_in[3];
    float* out = (float*)d_out;

    char* ws = (char*)d_ws;
    float* acc = (float*)ws;                                   // 3 floats
    float* g   = (float*)(ws + 256);                           // 1024x1800 fp32 (7.37 MB)
    float* T   = (float*)(ws + 256 + (size_t)B_ROWS * PERIOD * 4);          // 1800x280 (2.0 MB)
    float* scp = (float*)(ws + 256 + (size_t)B_ROWS * PERIOD * 4
                               + (size_t)PERIOD * NCOL * 4);   // 12x1024x280 (13.8 MB)

    hipMemsetAsync(acc, 0, 16, stream);

    trig<<<(PERIOD * NCOL + 255) / 256, 256, 0, stream>>>(T);
    fold_pearson<<<B_ROWS, 256, 0, stream>>>(pred, targ, g, acc);
    spectrum<<<dim3(B_ROWS / BLK_ROWS, NSPLIT), 256, 0, stream>>>(g, T, scp);
    post<<<B_ROWS, 64, 0, stream>>>(scp, hr, acc);
    finalize<<<1, 64, 0, stream>>>(acc, epoch, out);
}

// Round 3
// 153.724 us; speedup vs baseline: 1.3823x; 1.1936x over previous
//
#include <hip/hip_runtime.h>
#include <math.h>

#define B_ROWS   1024
#define N_SAMP   8192
#define NBINS    140
#define PERIOD   1800   // sin(2*pi*bpm*n/1800) has period 1800 in n for integer bpm
#define KP       2048   // K padded to 64 mfma steps of 32 (zeros in 1800..2047)
#define NCOLP    288    // 280 cols (140 sin | 140 cos) padded to 18 N-tiles of 16
#define NSPLIT   8      // K-split: 8 chunks of 256 k (8 mfma steps)
#define KSTEPS   8

typedef __attribute__((ext_vector_type(8))) short short8;   // 8 bf16 = 4 VGPRs (guide §3)
typedef __attribute__((ext_vector_type(4))) float f32x4;

__device__ __forceinline__ float wave_reduce_sum(float v) {
    #pragma unroll
    for (int off = 32; off > 0; off >>= 1) v += __shfl_xor(v, off, 64);
    return v;
}

__device__ __forceinline__ unsigned short f2bf(float x) {   // RNE float->bf16
    unsigned int u = __float_as_uint(x);
    unsigned int r = (u + 0x7fff + ((u >> 16) & 1)) >> 16;
    return (unsigned short)r;
}

// ---------------- Kernel 0: T^T[n][k] bf16: n<140 sin, 140..279 cos, 280..287 zero ------
// One thread per (n<144, k); n<140 computes sincos once, writes both sin and cos rows.
__global__ __launch_bounds__(256) void trig(unsigned short* __restrict__ Tt) {
    int idx = blockIdx.x * 256 + threadIdx.x;
    if (idx >= 144 * KP) return;
    int n = idx >> 11, k = idx & (KP - 1);
    if (n < NBINS) {
        float sv = 0.f, cv = 0.f;
        if (k < PERIOD) {
            int m = ((40 + n) * k) % PERIOD;  // integer-exact phase
            float ang = (6.28318530717958647692f / (float)PERIOD) * (float)m;
            __sincosf(ang, &sv, &cv);
        }
        Tt[(size_t)n * KP + k]            = f2bf(sv);
        Tt[(size_t)(NBINS + n) * KP + k]  = f2bf(cv);
    } else {                                  // n in 140..143 -> zero pad rows 280..287
        int zr = 280 + ((n - NBINS) << 1);
        Tt[(size_t)zr * KP + k]       = 0;
        Tt[(size_t)(zr + 1) * KP + k] = 0;
    }
}

// ---------------- Kernel 1: pearson moments + periodic fold of hann*pred -> bf16 --------
// 512 residue-quads per row (incl. zero pad 450..511), 2 balanced passes of 256 threads.
__global__ __launch_bounds__(256) void fold_pearson(const float* __restrict__ pred,
                                                    const float* __restrict__ targ,
                                                    unsigned short* __restrict__ gb,
                                                    float* __restrict__ acc) {
    const int row = blockIdx.x;
    const float* p = pred + (size_t)row * N_SAMP;
    const float* t = targ + (size_t)row * N_SAMP;
    float sx[4] = {0,0,0,0}, sy[4] = {0,0,0,0}, sxy[4] = {0,0,0,0};
    float sxx[4] = {0,0,0,0}, syy[4] = {0,0,0,0};
    const float hc = 6.28318530717958647692f / 8191.0f;  // np.hanning(8192)
    #pragma unroll
    for (int pass = 0; pass < 2; ++pass) {
        const int qd = threadIdx.x + 256 * pass;         // 0..511
        float ga[4] = {0,0,0,0};
        if (qd < 450) {
            #pragma unroll
            for (int q = 0; q < 5; ++q) {
                if (q < 4 || qd < 248) {                 // 4*248+7200 == 8192 exactly
                    const int n = 4 * qd + PERIOD * q;
                    const float4 pv = *(const float4*)(p + n);
                    const float4 tv = *(const float4*)(t + n);
                    const float pc[4] = {pv.x, pv.y, pv.z, pv.w};
                    const float tc[4] = {tv.x, tv.y, tv.z, tv.w};
                    #pragma unroll
                    for (int i = 0; i < 4; ++i) {
                        sx[i] += pc[i]; sy[i] += tc[i];
                        sxy[i] = fmaf(pc[i], tc[i], sxy[i]);
                        sxx[i] = fmaf(pc[i], pc[i], sxx[i]);
                        syy[i] = fmaf(tc[i], tc[i], syy[i]);
                        float h = 0.5f - 0.5f * __cosf(hc * (float)(n + i));
                        ga[i] = fmaf(pc[i], h, ga[i]);
                    }
                }
            }
        }
        ushort4 o;
        o.x = f2bf(ga[0]); o.y = f2bf(ga[1]); o.z = f2bf(ga[2]); o.w = f2bf(ga[3]);
        *(ushort4*)(gb + (size_t)row * KP + 4 * qd) = o;
    }
    float vals[5];
    vals[0] = sx[0]+sx[1]+sx[2]+sx[3];
    vals[1] = sy[0]+sy[1]+sy[2]+sy[3];
    vals[2] = sxy[0]+sxy[1]+sxy[2]+sxy[3];
    vals[3] = sxx[0]+sxx[1]+sxx[2]+sxx[3];
    vals[4] = syy[0]+syy[1]+syy[2]+syy[3];
    #pragma unroll
    for (int i = 0; i < 5; ++i) vals[i] = wave_reduce_sum(vals[i]);
    __shared__ float red[4][5];
    int wid = threadIdx.x >> 6, lane = threadIdx.x & 63;
    if (lane == 0) {
        #pragma unroll
        for (int i = 0; i < 5; ++i) red[wid][i] = vals[i];
    }
    __syncthreads();
    if (threadIdx.x == 0) {
        float m[5];
        #pragma unroll
        for (int i = 0; i < 5; ++i) m[i] = red[0][i] + red[1][i] + red[2][i] + red[3][i];
        const float N = (float)N_SAMP;
        float num = N * m[2] - m[0] * m[1];
        float den = sqrtf((N * m[3] - m[0] * m[0]) * (N * m[4] - m[1] * m[1]));
        atomicAdd(&acc[0], 1.0f - num / den);
    }
}

// ---------------- Kernel 2: MFMA GEMM  scp[ks] = gb(1024xKP) . Tt^T  --------------------
// grid (64 M-tiles, 8 K-splits), block 128 = 2 waves; wave w owns N-tiles [9w, 9w+9).
// A-frag: lane reads gb[mt*16 + (lane&15)][kbase + (lane>>4)*8 ..+7]   (16B contiguous)
// B-frag: lane reads Tt[t*16 + (lane&15)][kbase + (lane>>4)*8 ..+7]    (16B contiguous)
// C/D: col = lane&15, row = (lane>>4)*4 + reg (m89-verified).
__global__ __launch_bounds__(128) void spectrum(const unsigned short* __restrict__ gb,
                                                const unsigned short* __restrict__ Tt,
                                                float* __restrict__ scp) {
    const int lane = threadIdx.x & 63;
    const int wid  = threadIdx.x >> 6;          // 0..1
    const int mt   = blockIdx.x;
    const int ks   = blockIdx.y;
    const int t0   = wid * 9;
    const int mrow = mt * 16 + (lane & 15);
    const int kbase = ks * (KSTEPS * 32) + ((lane >> 4) << 3);
    const short* ga = (const short*)gb + (size_t)mrow * KP + kbase;
    const short* tb = (const short*)Tt + kbase;
    f32x4 acc[9];
    #pragma unroll
    for (int t = 0; t < 9; ++t) acc[t] = (f32x4){0.f, 0.f, 0.f, 0.f};
    #pragma unroll
    for (int s = 0; s < KSTEPS; ++s) {
        short8 a = *(const short8*)(ga + s * 32);
        #pragma unroll
        for (int t = 0; t < 9; ++t) {
            const int n = (t0 + t) * 16 + (lane & 15);
            short8 b = *(const short8*)(tb + (size_t)n * KP + s * 32);
            acc[t] = __builtin_amdgcn_mfma_f32_16x16x32_bf16(a, b, acc[t], 0, 0, 0);
        }
    }
    float* base = scp + ((size_t)ks * B_ROWS + (size_t)mt * 16) * NCOLP;
    const int col0  = lane & 15;
    const int rbase = (lane >> 4) * 4;
    #pragma unroll
    for (int t = 0; t < 9; ++t)
        #pragma unroll
        for (int i = 0; i < 4; ++i)
            base[(size_t)(rbase + i) * NCOLP + (t0 + t) * 16 + col0] = acc[t][i];
}

// ---------------- Kernel 3: reduce splits -> power -> normalize -> log_softmax -> CE+KL -
__global__ __launch_bounds__(64) void post(const float* __restrict__ scp,
                                           const int* __restrict__ hr,
                                           float* __restrict__ acc) {
    const int b = blockIdx.x;
    const int l = threadIdx.x;
    const int h = hr[b];
    float cav[3]; float casum = 0.f;
    #pragma unroll
    for (int u = 0; u < 3; ++u) {
        int j = l + 64 * u;
        float v = 0.f;
        if (j < NBINS) {
            float s = 0.f, c = 0.f;
            #pragma unroll
            for (int sp = 0; sp < NSPLIT; ++sp) {
                const float* pp = scp + ((size_t)sp * B_ROWS + b) * NCOLP;
                s += pp[j]; c += pp[NBINS + j];
            }
            v = fmaf(s, s, c * c);
        }
        cav[u] = v; casum += v;
    }
    casum = wave_reduce_sum(casum);
    const float inv = 1.0f / casum;
    float x[3]; float m = -1e30f;
    #pragma unroll
    for (int u = 0; u < 3; ++u) {
        int j = l + 64 * u;
        x[u] = cav[u] * inv;
        if (j < NBINS) m = fmaxf(m, x[u]);
    }
    #pragma unroll
    for (int off = 32; off > 0; off >>= 1) m = fmaxf(m, __shfl_xor(m, off, 64));
    float esum = 0.f;
    #pragma unroll
    for (int u = 0; u < 3; ++u) {
        int j = l + 64 * u;
        if (j < NBINS) esum += __expf(x[u] - m);
    }
    esum = wave_reduce_sum(esum);
    const float lse = m + __logf(esum);
    float ce = 0.f, kl = 0.f;
    #pragma unroll
    for (int u = 0; u < 3; ++u) {
        int j = l + 64 * u;
        if (j < NBINS) {
            float logp = x[u] - lse;
            if (j == h) ce = -logp;
            float d = (float)j - (float)h;
            float tt = __expf(-0.5f * d * d) * 0.39894228040143267794f;
            tt = fmaxf(tt, 1e-15f);
            kl += __expf(tt) * (tt - logp);
        }
    }
    ce = wave_reduce_sum(ce);
    kl = wave_reduce_sum(kl) * (1.0f / NBINS);
    if (l == 0) { atomicAdd(&acc[1], ce); atomicAdd(&acc[2], kl); }
}

// ---------------- Kernel 4: combine with curriculum alpha/beta -------------------------
__global__ void finalize(const float* __restrict__ acc, const int* __restrict__ epoch_p,
                         float* __restrict__ out) {
    if (threadIdx.x == 0 && blockIdx.x == 0) {
        float temporal = acc[0] * (1.0f / B_ROWS);
        float ce       = acc[1] * (1.0f / B_ROWS);
        float kl       = acc[2] * (1.0f / B_ROWS);
        int epoch = epoch_p[0];
        float alpha, beta;
        if (epoch > 25) { alpha = 0.05f; beta = 2.0f; }
        else {
            float e = (float)epoch / 25.0f;
            alpha = 0.1f * exp2f(-e);
            beta  = exp2f(e);
        }
        out[0] = alpha * temporal + beta * (ce + kl);
    }
}

extern "C" void kernel_launch(void* const* d_in, const int* in_sizes, int n_in,
                              void* d_out, int out_size, void* d_ws, size_t ws_size,
                              hipStream_t stream) {
    const int*   epoch = (const int*)d_in[0];
    const float* pred  = (const float*)d_in[1];
    const float* targ  = (const float*)d_in[2];
    const int*   hr    = (const int*)d_in[3];
    float* out = (float*)d_out;

    char* ws = (char*)d_ws;
    float*          acc = (float*)ws;                       // 3 floats
    unsigned short* gb  = (unsigned short*)(ws + 256);      // 1024 x 2048 bf16 (4 MB)
    unsigned short* Tt  = (unsigned short*)(ws + 256 + (size_t)B_ROWS * KP * 2);   // 288 x 2048 bf16
    float*          scp = (float*)(ws + 256 + (size_t)B_ROWS * KP * 2
                                        + (size_t)NCOLP * KP * 2);  // 8 x 1024 x 288 fp32

    hipMemsetAsync(acc, 0, 16, stream);

    trig<<<(144 * KP) / 256, 256, 0, stream>>>(Tt);
    fold_pearson<<<B_ROWS, 256, 0, stream>>>(pred, targ, gb, acc);
    spectrum<<<dim3(B_ROWS / 16, NSPLIT), 128, 0, stream>>>(gb, Tt, scp);
    post<<<B_ROWS, 64, 0, stream>>>(scp, hr, acc);
    finalize<<<1, 64, 0, stream>>>(acc, epoch, out);
}